// Round 1
// baseline (1449.542 us; speedup 1.0000x reference)
//
#include <hip/hip_runtime.h>
#include <hip/hip_bf16.h>

// Problem constants
#define BB 128          // batch
#define SS 128          // seq
#define EE 1024         // embed
#define NQ 8            // qubits
#define DD 256          // 2^NQ
#define LL 4            // layers
#define MM (BB*SS)      // 16384 rows

// ---------------------------------------------------------------------------
// Kernel A: fused qin = X@Wi+bi  +  8-qubit statevector sim -> psi (float2)
// One wave (64 lanes) per sample row; 4 complex amplitudes per lane.
// amplitude index idx = lane*4 + cc ; idx bit k: k<2 -> cc bit k, k>=2 -> lane bit k-2
// ---------------------------------------------------------------------------
__global__ __launch_bounds__(256) void qsim_kernel(
    const float* __restrict__ X, const float* __restrict__ Wi,
    const float* __restrict__ bi, const float* __restrict__ theta,
    float* __restrict__ psi)
{
    const int lane = threadIdx.x & 63;
    const int wid  = threadIdx.x >> 6;
    const int row  = blockIdx.x * 4 + wid;   // 4096 blocks * 4 waves = 16384

    // ---- qin = X[row] @ Wi + bi ----
    float acc[NQ];
#pragma unroll
    for (int j = 0; j < NQ; j++) acc[j] = 0.f;
    const float* xr = X + (size_t)row * EE;
#pragma unroll 4
    for (int k = lane; k < EE; k += 64) {
        float x = xr[k];
        const float4* w4 = (const float4*)(Wi + k * 8);
        float4 wa = w4[0], wb = w4[1];
        acc[0] += x * wa.x; acc[1] += x * wa.y; acc[2] += x * wa.z; acc[3] += x * wa.w;
        acc[4] += x * wb.x; acc[5] += x * wb.y; acc[6] += x * wb.z; acc[7] += x * wb.w;
    }
    float qin[NQ];
#pragma unroll
    for (int j = 0; j < NQ; j++) {
        float v = acc[j];
#pragma unroll
        for (int off = 32; off >= 1; off >>= 1) v += __shfl_xor(v, off, 64);
        qin[j] = v + bi[j];
    }

    // ---- statevector ----
    float sr[4], si[4];
#pragma unroll
    for (int c = 0; c < 4; c++) { sr[c] = 0.f; si[c] = 0.f; }
    if (lane == 0) sr[0] = 1.f;

    auto apply_ry = [&](int b, float th) {
        float s, c;
        __sincosf(0.5f * th, &s, &c);
        if (b >= 2) {
            int lb = b - 2;
            int bit = (lane >> lb) & 1;
            float sgn = bit ? s : -s;
#pragma unroll
            for (int cc = 0; cc < 4; cc++) {
                float pr = __shfl_xor(sr[cc], 1 << lb, 64);
                float pi = __shfl_xor(si[cc], 1 << lb, 64);
                sr[cc] = c * sr[cc] + sgn * pr;
                si[cc] = c * si[cc] + sgn * pi;
            }
        } else {
            int m = 1 << b;
            float tr[4], ti[4];
#pragma unroll
            for (int cc = 0; cc < 4; cc++) { tr[cc] = sr[cc]; ti[cc] = si[cc]; }
#pragma unroll
            for (int cc = 0; cc < 4; cc++) {
                int bit = (cc >> b) & 1;
                float sgn = bit ? s : -s;
                sr[cc] = c * tr[cc] + sgn * tr[cc ^ m];
                si[cc] = c * ti[cc] + sgn * ti[cc ^ m];
            }
        }
    };
    auto apply_rz = [&](int b, float th) {
        float sz, cr;
        __sincosf(0.5f * th, &sz, &cr);
#pragma unroll
        for (int cc = 0; cc < 4; cc++) {
            int bit = (b >= 2) ? ((lane >> (b - 2)) & 1) : ((cc >> b) & 1);
            float ci = bit ? sz : -sz;
            float r = sr[cc], i = si[cc];
            sr[cc] = r * cr - i * ci;
            si[cc] = r * ci + i * cr;
        }
    };
    auto apply_cnot = [&](int bc, int bt) {
        float pr[4], pi[4];
        if (bt >= 2) {
            int m = 1 << (bt - 2);
#pragma unroll
            for (int cc = 0; cc < 4; cc++) {
                pr[cc] = __shfl_xor(sr[cc], m, 64);
                pi[cc] = __shfl_xor(si[cc], m, 64);
            }
        } else {
            int m = 1 << bt;
#pragma unroll
            for (int cc = 0; cc < 4; cc++) {
                pr[cc] = sr[cc ^ m];
                pi[cc] = si[cc ^ m];
            }
        }
#pragma unroll
        for (int cc = 0; cc < 4; cc++) {
            int ctrl = (bc >= 2) ? ((lane >> (bc - 2)) & 1) : ((cc >> bc) & 1);
            sr[cc] = ctrl ? pr[cc] : sr[cc];
            si[cc] = ctrl ? pi[cc] : si[cc];
        }
    };

    // initial RY(x_q) on each qubit  (qubit q -> bit 7-q)
#pragma unroll
    for (int q = 0; q < NQ; q++) apply_ry(7 - q, qin[q]);
    // layers
#pragma unroll
    for (int l = 0; l < LL; l++) {
#pragma unroll
        for (int q = 0; q < NQ; q++) {
            apply_ry(7 - q, theta[(l * NQ + q) * 2 + 0]);
            apply_rz(7 - q, theta[(l * NQ + q) * 2 + 1]);
        }
#pragma unroll
        for (int q = 0; q < NQ; q++) {
            int t = (q + 1) & 7;
            apply_cnot(7 - q, 7 - t);
        }
    }

    // write psi row: lane writes 4 contiguous float2 (32B)
    float2* pout = (float2*)psi + (size_t)row * DD + lane * 4;
#pragma unroll
    for (int cc = 0; cc < 4; cc++) pout[cc] = make_float2(sr[cc], si[cc]);
}

// ---------------------------------------------------------------------------
// Kernel B/D/E: fp32 GEMM  C = A(MxK) @ W(KxN) + bias, optional batch strides
// 128x128 tile, BK=16, 256 threads, 8x8 per thread.
// ---------------------------------------------------------------------------
__global__ __launch_bounds__(256) void gemm_kernel(
    const float* __restrict__ A, const float* __restrict__ W,
    const float* __restrict__ bias, float* __restrict__ C,
    int M, int N, int K,
    long long strideA, long long strideW, long long strideC)
{
    const int bz = blockIdx.z;
    A += (size_t)bz * strideA;
    W += (size_t)bz * strideW;
    C += (size_t)bz * strideC;

    __shared__ float As[16][132];
    __shared__ float Bs[16][132];

    const int tid = threadIdx.x;
    const int tx = tid & 15, ty = tid >> 4;
    const int bm = blockIdx.x, bn = blockIdx.y;

    float accv[8][8] = {};

    const int lr = tid >> 2;           // A-load row 0..63 (and +64)
    const int lk = (tid & 3) << 2;     // A-load k offset 0,4,8,12
    const int wk = tid >> 4;           // B-load k 0..15
    const int wc = (tid & 15) << 3;    // B-load col offset 0..120

    for (int kt = 0; kt < K; kt += 16) {
#pragma unroll
        for (int h = 0; h < 2; h++) {
            int r = lr + h * 64;
            float4 a4 = *(const float4*)(A + (size_t)(bm * 128 + r) * K + kt + lk);
            As[lk + 0][r] = a4.x; As[lk + 1][r] = a4.y;
            As[lk + 2][r] = a4.z; As[lk + 3][r] = a4.w;
        }
        {
            const float* wp = W + (size_t)(kt + wk) * N + bn * 128 + wc;
            float4 b0 = *(const float4*)(wp);
            float4 b1 = *(const float4*)(wp + 4);
            *(float4*)&Bs[wk][wc] = b0;
            *(float4*)&Bs[wk][wc + 4] = b1;
        }
        __syncthreads();
#pragma unroll
        for (int k = 0; k < 16; k++) {
            float4 a0 = *(const float4*)&As[k][ty * 4];
            float4 a1 = *(const float4*)&As[k][64 + ty * 4];
            float4 b0 = *(const float4*)&Bs[k][tx * 4];
            float4 b1 = *(const float4*)&Bs[k][64 + tx * 4];
            float ar[8] = {a0.x, a0.y, a0.z, a0.w, a1.x, a1.y, a1.z, a1.w};
            float br[8] = {b0.x, b0.y, b0.z, b0.w, b1.x, b1.y, b1.z, b1.w};
#pragma unroll
            for (int i = 0; i < 8; i++)
#pragma unroll
                for (int j = 0; j < 8; j++)
                    accv[i][j] += ar[i] * br[j];
        }
        __syncthreads();
    }

    // epilogue: rows {ty*4+i, 64+ty*4+i}, cols {tx*4+j, 64+tx*4+j}
#pragma unroll
    for (int i = 0; i < 8; i++) {
        int r = bm * 128 + ((i < 4) ? (ty * 4 + i) : (64 + ty * 4 + i - 4));
#pragma unroll
        for (int jh = 0; jh < 2; jh++) {
            int c0 = bn * 128 + jh * 64 + tx * 4;
            float4 v;
            v.x = accv[i][jh * 4 + 0];
            v.y = accv[i][jh * 4 + 1];
            v.z = accv[i][jh * 4 + 2];
            v.w = accv[i][jh * 4 + 3];
            if (bias) {
                v.x += bias[c0 + 0]; v.y += bias[c0 + 1];
                v.z += bias[c0 + 2]; v.w += bias[c0 + 3];
            }
            *(float4*)(C + (size_t)r * N + c0) = v;
        }
    }
}

// ---------------------------------------------------------------------------
// Kernel C: K[b][s][:] = |psi_s . conj(psi_t)|^2 / sqrt(8) + cos(phi_t-phi_s),
// softmax over t, write attn. One 128-thread block per (b,s) row.
// ---------------------------------------------------------------------------
__global__ __launch_bounds__(128) void attn_kernel(
    const float* __restrict__ psi, const float* __restrict__ phi,
    float* __restrict__ attn)
{
    const int s = blockIdx.x;
    const int b = blockIdx.y;
    const int t = threadIdx.x;

    __shared__ float ps[2 * DD];       // psi[b][s][:] re,im interleaved
    __shared__ float wred[2];

    const float* prow = psi + ((size_t)(b * SS + s)) * (2 * DD);
    ((float4*)ps)[t] = ((const float4*)prow)[t];   // 128 * 16B = 2KB
    __syncthreads();

    const float* pt = psi + ((size_t)(b * SS + t)) * (2 * DD);
    float re = 0.f, im = 0.f;
#pragma unroll 8
    for (int d = 0; d < DD; d += 2) {
        float4 a2 = ((const float4*)ps)[d >> 1];
        float4 c2 = *(const float4*)(pt + 2 * d);
        re += a2.x * c2.x + a2.y * c2.y + a2.z * c2.z + a2.w * c2.w;
        im += a2.y * c2.x - a2.x * c2.y + a2.w * c2.z - a2.z * c2.w;
    }
    float Kst = (re * re + im * im) * 0.35355339059327373f
              + __cosf(phi[t] - phi[s]);

    // max over 128 threads (2 waves)
    float mx = Kst;
#pragma unroll
    for (int off = 32; off >= 1; off >>= 1) mx = fmaxf(mx, __shfl_xor(mx, off, 64));
    if ((t & 63) == 0) wred[t >> 6] = mx;
    __syncthreads();
    mx = fmaxf(wred[0], wred[1]);
    float p = __expf(Kst - mx);
    float sm = p;
#pragma unroll
    for (int off = 32; off >= 1; off >>= 1) sm += __shfl_xor(sm, off, 64);
    __syncthreads();
    if ((t & 63) == 0) wred[t >> 6] = sm;
    __syncthreads();
    sm = wred[0] + wred[1];

    attn[((size_t)(b * SS + s)) * SS + t] = p / sm;
}

// ---------------------------------------------------------------------------
extern "C" void kernel_launch(void* const* d_in, const int* in_sizes, int n_in,
                              void* d_out, int out_size, void* d_ws, size_t ws_size,
                              hipStream_t stream) {
    const float* X     = (const float*)d_in[0];
    const float* Wi    = (const float*)d_in[1];
    const float* bi    = (const float*)d_in[2];
    const float* Wv    = (const float*)d_in[3];
    const float* bv    = (const float*)d_in[4];
    const float* Wo    = (const float*)d_in[5];
    const float* bo    = (const float*)d_in[6];
    const float* theta = (const float*)d_in[7];
    const float* phi   = (const float*)d_in[8];

    float* y    = (float*)d_out;                 // 16777216 floats
    float* attn = y + (size_t)MM * EE;           // 2097152 floats

    float* psi = (float*)d_ws;                   // 16384*256*2 = 8388608 floats
    float* V   = psi + (size_t)MM * 2 * DD;      // 16777216 floats
    float* o2  = V + (size_t)MM * EE;            // 16777216 floats

    // 1) psi
    qsim_kernel<<<MM / 4, 256, 0, stream>>>(X, Wi, bi, theta, psi);
    // 2) V = X @ Wv + bv
    gemm_kernel<<<dim3(MM / 128, EE / 128, 1), 256, 0, stream>>>(
        X, Wv, bv, V, MM, EE, EE, 0, 0, 0);
    // 3) attn
    attn_kernel<<<dim3(SS, BB), 128, 0, stream>>>(psi, phi, attn);
    // 4) out = attn @ V (batched)
    gemm_kernel<<<dim3(1, EE / 128, BB), 256, 0, stream>>>(
        attn, V, nullptr, o2, SS, EE, SS,
        (long long)SS * SS, (long long)SS * EE, (long long)SS * EE);
    // 5) y = out @ Wo + bo
    gemm_kernel<<<dim3(MM / 128, EE / 128, 1), 256, 0, stream>>>(
        o2, Wo, bo, y, MM, EE, EE, 0, 0, 0);
}

// Round 2
// 501.508 us; speedup vs baseline: 2.8904x; 2.8904x over previous
//
#include <hip/hip_runtime.h>
#include <hip/hip_bf16.h>

#define BB 128
#define SS 128
#define EE 1024
#define NQ 8
#define DD 256
#define LL 4
#define MM (BB*SS)

typedef unsigned short bf16s;
typedef __attribute__((ext_vector_type(8))) short bf16x8;
typedef __attribute__((ext_vector_type(4))) float f32x4;

#define AS1 __attribute__((address_space(1)))
#define AS3 __attribute__((address_space(3)))

__device__ __forceinline__ unsigned short f2bf(float x) {
    unsigned u = __float_as_uint(x);
    u += 0x7fffu + ((u >> 16) & 1u);
    return (unsigned short)(u >> 16);
}
__device__ __forceinline__ float bfl(unsigned v) { return __uint_as_float(v << 16); }
__device__ __forceinline__ float bfh(unsigned v) { return __uint_as_float(v & 0xffff0000u); }

// ---------------------------------------------------------------------------
// fp32 -> bf16 elementwise convert (X)
// ---------------------------------------------------------------------------
__global__ __launch_bounds__(256) void convert_kernel(
    const float* __restrict__ in, bf16s* __restrict__ out, int n4)
{
    int i = blockIdx.x * 256 + threadIdx.x;
    if (i < n4) {
        float4 v = ((const float4*)in)[i];
        ushort4 o;
        o.x = f2bf(v.x); o.y = f2bf(v.y); o.z = f2bf(v.z); o.w = f2bf(v.w);
        ((ushort4*)out)[i] = o;
    }
}

// ---------------------------------------------------------------------------
// fp32 RxC -> bf16 CxR transpose-convert (weights)
// ---------------------------------------------------------------------------
__global__ __launch_bounds__(256) void transpose_conv_kernel(
    const float* __restrict__ in, bf16s* __restrict__ out, int R, int C)
{
    __shared__ float t[32][33];
    int bx = blockIdx.x * 32, by = blockIdx.y * 32;
    int lx = threadIdx.x & 31, ly = threadIdx.x >> 5;
#pragma unroll
    for (int i = 0; i < 32; i += 8)
        t[ly + i][lx] = in[(size_t)(by + ly + i) * C + bx + lx];
    __syncthreads();
#pragma unroll
    for (int i = 0; i < 32; i += 8)
        out[(size_t)(bx + ly + i) * R + by + lx] = f2bf(t[lx][ly + i]);
}

// ---------------------------------------------------------------------------
// Kernel A: fused qin = X@Wi+bi  +  8-qubit statevector sim -> psi (float2)
// ---------------------------------------------------------------------------
__global__ __launch_bounds__(256) void qsim_kernel(
    const float* __restrict__ X, const float* __restrict__ Wi,
    const float* __restrict__ bi, const float* __restrict__ theta,
    float* __restrict__ psi)
{
    const int lane = threadIdx.x & 63;
    const int wid  = threadIdx.x >> 6;
    const int row  = blockIdx.x * 4 + wid;

    float acc[NQ];
#pragma unroll
    for (int j = 0; j < NQ; j++) acc[j] = 0.f;
    const float* xr = X + (size_t)row * EE;
#pragma unroll 4
    for (int k = lane; k < EE; k += 64) {
        float x = xr[k];
        const float4* w4 = (const float4*)(Wi + k * 8);
        float4 wa = w4[0], wb = w4[1];
        acc[0] += x * wa.x; acc[1] += x * wa.y; acc[2] += x * wa.z; acc[3] += x * wa.w;
        acc[4] += x * wb.x; acc[5] += x * wb.y; acc[6] += x * wb.z; acc[7] += x * wb.w;
    }
    float qin[NQ];
#pragma unroll
    for (int j = 0; j < NQ; j++) {
        float v = acc[j];
#pragma unroll
        for (int off = 32; off >= 1; off >>= 1) v += __shfl_xor(v, off, 64);
        qin[j] = v + bi[j];
    }

    float sr[4], si[4];
#pragma unroll
    for (int c = 0; c < 4; c++) { sr[c] = 0.f; si[c] = 0.f; }
    if (lane == 0) sr[0] = 1.f;

    auto apply_ry = [&](int b, float th) {
        float s, c;
        __sincosf(0.5f * th, &s, &c);
        if (b >= 2) {
            int lb = b - 2;
            int bit = (lane >> lb) & 1;
            float sgn = bit ? s : -s;
#pragma unroll
            for (int cc = 0; cc < 4; cc++) {
                float pr = __shfl_xor(sr[cc], 1 << lb, 64);
                float pi = __shfl_xor(si[cc], 1 << lb, 64);
                sr[cc] = c * sr[cc] + sgn * pr;
                si[cc] = c * si[cc] + sgn * pi;
            }
        } else {
            int m = 1 << b;
            float tr[4], ti[4];
#pragma unroll
            for (int cc = 0; cc < 4; cc++) { tr[cc] = sr[cc]; ti[cc] = si[cc]; }
#pragma unroll
            for (int cc = 0; cc < 4; cc++) {
                int bit = (cc >> b) & 1;
                float sgn = bit ? s : -s;
                sr[cc] = c * tr[cc] + sgn * tr[cc ^ m];
                si[cc] = c * ti[cc] + sgn * ti[cc ^ m];
            }
        }
    };
    auto apply_rz = [&](int b, float th) {
        float sz, cr;
        __sincosf(0.5f * th, &sz, &cr);
#pragma unroll
        for (int cc = 0; cc < 4; cc++) {
            int bit = (b >= 2) ? ((lane >> (b - 2)) & 1) : ((cc >> b) & 1);
            float ci = bit ? sz : -sz;
            float r = sr[cc], i = si[cc];
            sr[cc] = r * cr - i * ci;
            si[cc] = r * ci + i * cr;
        }
    };
    auto apply_cnot = [&](int bc, int bt) {
        float pr[4], pi[4];
        if (bt >= 2) {
            int m = 1 << (bt - 2);
#pragma unroll
            for (int cc = 0; cc < 4; cc++) {
                pr[cc] = __shfl_xor(sr[cc], m, 64);
                pi[cc] = __shfl_xor(si[cc], m, 64);
            }
        } else {
            int m = 1 << bt;
#pragma unroll
            for (int cc = 0; cc < 4; cc++) {
                pr[cc] = sr[cc ^ m];
                pi[cc] = si[cc ^ m];
            }
        }
#pragma unroll
        for (int cc = 0; cc < 4; cc++) {
            int ctrl = (bc >= 2) ? ((lane >> (bc - 2)) & 1) : ((cc >> bc) & 1);
            sr[cc] = ctrl ? pr[cc] : sr[cc];
            si[cc] = ctrl ? pi[cc] : si[cc];
        }
    };

#pragma unroll
    for (int q = 0; q < NQ; q++) apply_ry(7 - q, qin[q]);
#pragma unroll
    for (int l = 0; l < LL; l++) {
#pragma unroll
        for (int q = 0; q < NQ; q++) {
            apply_ry(7 - q, theta[(l * NQ + q) * 2 + 0]);
            apply_rz(7 - q, theta[(l * NQ + q) * 2 + 1]);
        }
#pragma unroll
        for (int q = 0; q < NQ; q++) {
            int t = (q + 1) & 7;
            apply_cnot(7 - q, 7 - t);
        }
    }

    float2* pout = (float2*)psi + (size_t)row * DD + lane * 4;
#pragma unroll
    for (int cc = 0; cc < 4; cc++) pout[cc] = make_float2(sr[cc], si[cc]);
}

// ---------------------------------------------------------------------------
// MFMA bf16 GEMM: C[M][N] = A[M][K] @ Bt[N][K]^T (+bias). m97-style.
// 128x128 tile, BK=32, 256 threads = 4 waves, each wave 64x64.
// ---------------------------------------------------------------------------
template<bool OUT_BF16>
__global__ __launch_bounds__(256) void mfma_gemm(
    const bf16s* __restrict__ A, const bf16s* __restrict__ Bt,
    const float* __restrict__ bias, void* __restrict__ Cv,
    int M, int N, int K,
    long long sA, long long sB, long long sC)
{
    __shared__ bf16s As[128 * 32];
    __shared__ bf16s Bs[128 * 32];

    const int tid  = threadIdx.x;
    const int wave = tid >> 6, lane = tid & 63;
    const int quad = lane >> 4, lr = lane & 15;
    const int wm = (wave >> 1) * 64, wn = (wave & 1) * 64;
    const int m0 = blockIdx.x * 128, n0 = blockIdx.y * 128;

    A  += (size_t)blockIdx.z * sA;
    Bt += (size_t)blockIdx.z * sB;

    f32x4 acc[4][4];
#pragma unroll
    for (int i = 0; i < 4; i++)
#pragma unroll
        for (int j = 0; j < 4; j++) acc[i][j] = (f32x4){0.f, 0.f, 0.f, 0.f};

    for (int kt = 0; kt < K; kt += 32) {
#pragma unroll
        for (int j = 0; j < 2; j++) {
            int ch = j * 256 + tid;
            int row = ch >> 2, kc = (ch & 3) * 8;
            __builtin_amdgcn_global_load_lds(
                (AS1 const void*)(A + (size_t)(m0 + row) * K + kt + kc),
                (AS3 void*)(As + (size_t)(j * 256 + wave * 64) * 8), 16, 0, 0);
            __builtin_amdgcn_global_load_lds(
                (AS1 const void*)(Bt + (size_t)(n0 + row) * K + kt + kc),
                (AS3 void*)(Bs + (size_t)(j * 256 + wave * 64) * 8), 16, 0, 0);
        }
        __syncthreads();

        bf16x8 af[4], bfr[4];
#pragma unroll
        for (int i = 0; i < 4; i++)
            af[i] = *(const bf16x8*)(As + (wm + i * 16 + lr) * 32 + quad * 8);
#pragma unroll
        for (int j = 0; j < 4; j++)
            bfr[j] = *(const bf16x8*)(Bs + (wn + j * 16 + lr) * 32 + quad * 8);
#pragma unroll
        for (int i = 0; i < 4; i++)
#pragma unroll
            for (int j = 0; j < 4; j++)
                acc[i][j] = __builtin_amdgcn_mfma_f32_16x16x32_bf16(
                    af[i], bfr[j], acc[i][j], 0, 0, 0);
        __syncthreads();
    }

    float* Cf = (float*)Cv + (size_t)blockIdx.z * sC;
    bf16s* Cb = (bf16s*)Cv + (size_t)blockIdx.z * sC;
#pragma unroll
    for (int i = 0; i < 4; i++) {
        int row0 = m0 + wm + i * 16 + quad * 4;
#pragma unroll
        for (int j = 0; j < 4; j++) {
            int col = n0 + wn + j * 16 + lr;
            float bb = bias ? bias[col] : 0.f;
#pragma unroll
            for (int r = 0; r < 4; r++) {
                float v = acc[i][j][r] + bb;
                if (OUT_BF16) Cb[(size_t)(row0 + r) * N + col] = f2bf(v);
                else          Cf[(size_t)(row0 + r) * N + col] = v;
            }
        }
    }
}

// ---------------------------------------------------------------------------
// attn: per (batch, 64-row s-tile): G = psi.psi^H tile, K, softmax, attn.
// 512 threads: 32x16 thread grid, 4 rows x 4 cols per thread.
// ---------------------------------------------------------------------------
__global__ __launch_bounds__(512) void attn_kernel(
    const float* __restrict__ psi, const float* __restrict__ phi,
    float* __restrict__ attn)
{
    __shared__ float Bs[128 * 36];
    const int tid = threadIdx.x;
    const int b = blockIdx.y;
    const int s0 = blockIdx.x * 64;
    const int tx = tid & 31, ty = tid >> 5;
    const float* pb = psi + (size_t)b * 128 * 512;

    float re[4][4] = {}, im[4][4] = {};

    for (int kt = 0; kt < 16; kt++) {
        int fo = kt * 32;
#pragma unroll
        for (int q = 0; q < 2; q++) {
            int c = q * 512 + tid;
            int row = c >> 3, off = (c & 7) * 4;
            *(float4*)&Bs[row * 36 + off] =
                *(const float4*)&pb[(size_t)row * 512 + fo + off];
        }
        __syncthreads();
#pragma unroll 4
        for (int k = 0; k < 16; k++) {
            float2 av[4], bv2[4];
#pragma unroll
            for (int i = 0; i < 4; i++)
                av[i] = *(const float2*)&Bs[(s0 + ty * 4 + i) * 36 + 2 * k];
#pragma unroll
            for (int j = 0; j < 4; j++)
                bv2[j] = *(const float2*)&Bs[(tx * 4 + j) * 36 + 2 * k];
#pragma unroll
            for (int i = 0; i < 4; i++)
#pragma unroll
                for (int j = 0; j < 4; j++) {
                    re[i][j] += av[i].x * bv2[j].x + av[i].y * bv2[j].y;
                    im[i][j] += av[i].y * bv2[j].x - av[i].x * bv2[j].y;
                }
        }
        __syncthreads();
    }

    const float isq = 0.35355339059327373f;
    float Kv[4][4], phr[4], phc[4];
#pragma unroll
    for (int i = 0; i < 4; i++) phr[i] = phi[s0 + ty * 4 + i];
#pragma unroll
    for (int j = 0; j < 4; j++) phc[j] = phi[tx * 4 + j];
#pragma unroll
    for (int i = 0; i < 4; i++)
#pragma unroll
        for (int j = 0; j < 4; j++)
            Kv[i][j] = (re[i][j] * re[i][j] + im[i][j] * im[i][j]) * isq
                     + __cosf(phc[j] - phr[i]);

#pragma unroll
    for (int i = 0; i < 4; i++) {
        float mx = fmaxf(fmaxf(Kv[i][0], Kv[i][1]), fmaxf(Kv[i][2], Kv[i][3]));
#pragma unroll
        for (int off = 1; off <= 16; off <<= 1) mx = fmaxf(mx, __shfl_xor(mx, off, 64));
        float sm = 0.f;
#pragma unroll
        for (int j = 0; j < 4; j++) { Kv[i][j] = __expf(Kv[i][j] - mx); sm += Kv[i][j]; }
#pragma unroll
        for (int off = 1; off <= 16; off <<= 1) sm += __shfl_xor(sm, off, 64);
        float r = 1.f / sm;
        float4 o = make_float4(Kv[i][0] * r, Kv[i][1] * r, Kv[i][2] * r, Kv[i][3] * r);
        *(float4*)&attn[((size_t)(b * 128 + s0 + ty * 4 + i)) * 128 + tx * 4] = o;
    }
}

// ---------------------------------------------------------------------------
// GEMM2: o2 = attn @ V  (A fp32 MxK, B bf16 KxN row-major, C bf16), batched.
// 128x128 tile, BK=16, 256 threads, 8x8 per thread.
// ---------------------------------------------------------------------------
__global__ __launch_bounds__(256) void gemm2_kernel(
    const float* __restrict__ A, const bf16s* __restrict__ Bb,
    bf16s* __restrict__ C, int M, int N, int K,
    long long strideA, long long strideB, long long strideC)
{
    const int bz = blockIdx.z;
    A  += (size_t)bz * strideA;
    Bb += (size_t)bz * strideB;
    C  += (size_t)bz * strideC;

    __shared__ float As[16][132];
    __shared__ float Bs[16][132];

    const int tid = threadIdx.x;
    const int tx = tid & 15, ty = tid >> 4;
    const int bm = blockIdx.x, bn = blockIdx.y;

    float accv[8][8] = {};

    const int lrr = tid >> 2;
    const int lk = (tid & 3) << 2;
    const int wk = tid >> 4;
    const int wc = (tid & 15) << 3;

    for (int kt = 0; kt < K; kt += 16) {
#pragma unroll
        for (int h = 0; h < 2; h++) {
            int r = lrr + h * 64;
            float4 a4 = *(const float4*)(A + (size_t)(bm * 128 + r) * K + kt + lk);
            As[lk + 0][r] = a4.x; As[lk + 1][r] = a4.y;
            As[lk + 2][r] = a4.z; As[lk + 3][r] = a4.w;
        }
        {
            const bf16s* wp = Bb + (size_t)(kt + wk) * N + bn * 128 + wc;
            uint4 u = *(const uint4*)wp;
            Bs[wk][wc + 0] = bfl(u.x); Bs[wk][wc + 1] = bfh(u.x);
            Bs[wk][wc + 2] = bfl(u.y); Bs[wk][wc + 3] = bfh(u.y);
            Bs[wk][wc + 4] = bfl(u.z); Bs[wk][wc + 5] = bfh(u.z);
            Bs[wk][wc + 6] = bfl(u.w); Bs[wk][wc + 7] = bfh(u.w);
        }
        __syncthreads();
#pragma unroll
        for (int k = 0; k < 16; k++) {
            float4 a0 = *(const float4*)&As[k][ty * 4];
            float4 a1 = *(const float4*)&As[k][64 + ty * 4];
            float4 b0 = *(const float4*)&Bs[k][tx * 4];
            float4 b1 = *(const float4*)&Bs[k][64 + tx * 4];
            float ar[8] = {a0.x, a0.y, a0.z, a0.w, a1.x, a1.y, a1.z, a1.w};
            float br[8] = {b0.x, b0.y, b0.z, b0.w, b1.x, b1.y, b1.z, b1.w};
#pragma unroll
            for (int i = 0; i < 8; i++)
#pragma unroll
                for (int j = 0; j < 8; j++)
                    accv[i][j] += ar[i] * br[j];
        }
        __syncthreads();
    }

#pragma unroll
    for (int i = 0; i < 8; i++) {
        int r = bm * 128 + ((i < 4) ? (ty * 4 + i) : (64 + ty * 4 + i - 4));
#pragma unroll
        for (int jh = 0; jh < 2; jh++) {
            int c0 = bn * 128 + jh * 64 + tx * 4;
            ushort4 ov;
            ov.x = f2bf(accv[i][jh * 4 + 0]);
            ov.y = f2bf(accv[i][jh * 4 + 1]);
            ov.z = f2bf(accv[i][jh * 4 + 2]);
            ov.w = f2bf(accv[i][jh * 4 + 3]);
            *(ushort4*)(C + (size_t)r * N + c0) = ov;
        }
    }
}

// ---------------------------------------------------------------------------
extern "C" void kernel_launch(void* const* d_in, const int* in_sizes, int n_in,
                              void* d_out, int out_size, void* d_ws, size_t ws_size,
                              hipStream_t stream) {
    const float* X     = (const float*)d_in[0];
    const float* Wi    = (const float*)d_in[1];
    const float* bi    = (const float*)d_in[2];
    const float* Wv    = (const float*)d_in[3];
    const float* bv    = (const float*)d_in[4];
    const float* Wo    = (const float*)d_in[5];
    const float* bo    = (const float*)d_in[6];
    const float* theta = (const float*)d_in[7];
    const float* phi   = (const float*)d_in[8];

    float* y    = (float*)d_out;
    float* attn = y + (size_t)MM * EE;

    float* psi = (float*)d_ws;                       // 16384*512 floats
    bf16s* Xb  = (bf16s*)(psi + (size_t)MM * 512);   // 16384*1024 bf16
    bf16s* Vb  = Xb + (size_t)MM * EE;               // 16384*1024 bf16
    bf16s* o2b = Vb + (size_t)MM * EE;               // 16384*1024 bf16
    bf16s* Wvt = o2b + (size_t)MM * EE;              // 1024*1024 bf16 (transposed)
    bf16s* Wot = Wvt + (size_t)EE * EE;              // 1024*1024 bf16 (transposed)

    // conversions
    convert_kernel<<<(MM * EE / 4 + 255) / 256, 256, 0, stream>>>(X, Xb, MM * EE / 4);
    transpose_conv_kernel<<<dim3(32, 32), 256, 0, stream>>>(Wv, Wvt, EE, EE);
    transpose_conv_kernel<<<dim3(32, 32), 256, 0, stream>>>(Wo, Wot, EE, EE);
    // psi
    qsim_kernel<<<MM / 4, 256, 0, stream>>>(X, Wi, bi, theta, psi);
    // V = X @ Wv + bv   (bf16 out)
    mfma_gemm<true><<<dim3(MM / 128, EE / 128, 1), 256, 0, stream>>>(
        Xb, Wvt, bv, Vb, MM, EE, EE, 0, 0, 0);
    // attn
    attn_kernel<<<dim3(2, BB), 512, 0, stream>>>(psi, phi, attn);
    // o2 = attn @ V  (bf16 out)
    gemm2_kernel<<<dim3(1, EE / 128, BB), 256, 0, stream>>>(
        attn, Vb, o2b, SS, EE, SS,
        (long long)SS * SS, (long long)SS * EE, (long long)SS * EE);
    // y = o2 @ Wo + bo  (fp32 out)
    mfma_gemm<false><<<dim3(MM / 128, EE / 128, 1), 256, 0, stream>>>(
        o2b, Wot, bo, y, MM, EE, EE, 0, 0, 0);
}

// Round 3
// 392.539 us; speedup vs baseline: 3.6927x; 1.2776x over previous
//
#include <hip/hip_runtime.h>
#include <hip/hip_bf16.h>

#define BB 128
#define SS 128
#define EE 1024
#define NQ 8
#define DD 256
#define LL 4
#define MM (BB*SS)

typedef unsigned short bf16s;
typedef __attribute__((ext_vector_type(8))) short bf16x8;
typedef __attribute__((ext_vector_type(4))) float f32x4;

#define AS1 __attribute__((address_space(1)))
#define AS3 __attribute__((address_space(3)))

__device__ __forceinline__ unsigned short f2bf(float x) {
    unsigned u = __float_as_uint(x);
    u += 0x7fffu + ((u >> 16) & 1u);
    return (unsigned short)(u >> 16);
}

// ---------------------------------------------------------------------------
// fp32 -> bf16 elementwise convert (X)
// ---------------------------------------------------------------------------
__global__ __launch_bounds__(256) void convert_kernel(
    const float* __restrict__ in, bf16s* __restrict__ out, int n4)
{
    int i = blockIdx.x * 256 + threadIdx.x;
    if (i < n4) {
        float4 v = ((const float4*)in)[i];
        ushort4 o;
        o.x = f2bf(v.x); o.y = f2bf(v.y); o.z = f2bf(v.z); o.w = f2bf(v.w);
        ((ushort4*)out)[i] = o;
    }
}

// ---------------------------------------------------------------------------
// fp32 RxC -> bf16 CxR transpose-convert (weights)
// ---------------------------------------------------------------------------
__global__ __launch_bounds__(256) void transpose_conv_kernel(
    const float* __restrict__ in, bf16s* __restrict__ out, int R, int C)
{
    __shared__ float t[32][33];
    int bx = blockIdx.x * 32, by = blockIdx.y * 32;
    int lx = threadIdx.x & 31, ly = threadIdx.x >> 5;
#pragma unroll
    for (int i = 0; i < 32; i += 8)
        t[ly + i][lx] = in[(size_t)(by + ly + i) * C + bx + lx];
    __syncthreads();
#pragma unroll
    for (int i = 0; i < 32; i += 8)
        out[(size_t)(bx + ly + i) * R + by + lx] = f2bf(t[lx][ly + i]);
}

// ---------------------------------------------------------------------------
// Kernel A: fused qin = X@Wi+bi  +  8-qubit statevector sim.
// Emits P1 = [Re|Im], P2 = [Im|-Re] rows in bf16 (512 each).
// ---------------------------------------------------------------------------
__global__ __launch_bounds__(256) void qsim_kernel(
    const float* __restrict__ X, const float* __restrict__ Wi,
    const float* __restrict__ bi, const float* __restrict__ theta,
    bf16s* __restrict__ P1, bf16s* __restrict__ P2)
{
    const int lane = threadIdx.x & 63;
    const int wid  = threadIdx.x >> 6;
    const int row  = blockIdx.x * 4 + wid;

    float acc[NQ];
#pragma unroll
    for (int j = 0; j < NQ; j++) acc[j] = 0.f;
    const float* xr = X + (size_t)row * EE;
#pragma unroll 4
    for (int k = lane; k < EE; k += 64) {
        float x = xr[k];
        const float4* w4 = (const float4*)(Wi + k * 8);
        float4 wa = w4[0], wb = w4[1];
        acc[0] += x * wa.x; acc[1] += x * wa.y; acc[2] += x * wa.z; acc[3] += x * wa.w;
        acc[4] += x * wb.x; acc[5] += x * wb.y; acc[6] += x * wb.z; acc[7] += x * wb.w;
    }
    float qin[NQ];
#pragma unroll
    for (int j = 0; j < NQ; j++) {
        float v = acc[j];
#pragma unroll
        for (int off = 32; off >= 1; off >>= 1) v += __shfl_xor(v, off, 64);
        qin[j] = v + bi[j];
    }

    float sr[4], si[4];
#pragma unroll
    for (int c = 0; c < 4; c++) { sr[c] = 0.f; si[c] = 0.f; }
    if (lane == 0) sr[0] = 1.f;

    auto apply_ry = [&](int b, float th) {
        float s, c;
        __sincosf(0.5f * th, &s, &c);
        if (b >= 2) {
            int lb = b - 2;
            int bit = (lane >> lb) & 1;
            float sgn = bit ? s : -s;
#pragma unroll
            for (int cc = 0; cc < 4; cc++) {
                float pr = __shfl_xor(sr[cc], 1 << lb, 64);
                float pi = __shfl_xor(si[cc], 1 << lb, 64);
                sr[cc] = c * sr[cc] + sgn * pr;
                si[cc] = c * si[cc] + sgn * pi;
            }
        } else {
            int m = 1 << b;
            float tr[4], ti[4];
#pragma unroll
            for (int cc = 0; cc < 4; cc++) { tr[cc] = sr[cc]; ti[cc] = si[cc]; }
#pragma unroll
            for (int cc = 0; cc < 4; cc++) {
                int bit = (cc >> b) & 1;
                float sgn = bit ? s : -s;
                sr[cc] = c * tr[cc] + sgn * tr[cc ^ m];
                si[cc] = c * ti[cc] + sgn * ti[cc ^ m];
            }
        }
    };
    auto apply_rz = [&](int b, float th) {
        float sz, cr;
        __sincosf(0.5f * th, &sz, &cr);
#pragma unroll
        for (int cc = 0; cc < 4; cc++) {
            int bit = (b >= 2) ? ((lane >> (b - 2)) & 1) : ((cc >> b) & 1);
            float ci = bit ? sz : -sz;
            float r = sr[cc], i = si[cc];
            sr[cc] = r * cr - i * ci;
            si[cc] = r * ci + i * cr;
        }
    };
    auto apply_cnot = [&](int bc, int bt) {
        float pr[4], pi[4];
        if (bt >= 2) {
            int m = 1 << (bt - 2);
#pragma unroll
            for (int cc = 0; cc < 4; cc++) {
                pr[cc] = __shfl_xor(sr[cc], m, 64);
                pi[cc] = __shfl_xor(si[cc], m, 64);
            }
        } else {
            int m = 1 << bt;
#pragma unroll
            for (int cc = 0; cc < 4; cc++) {
                pr[cc] = sr[cc ^ m];
                pi[cc] = si[cc ^ m];
            }
        }
#pragma unroll
        for (int cc = 0; cc < 4; cc++) {
            int ctrl = (bc >= 2) ? ((lane >> (bc - 2)) & 1) : ((cc >> bc) & 1);
            sr[cc] = ctrl ? pr[cc] : sr[cc];
            si[cc] = ctrl ? pi[cc] : si[cc];
        }
    };

#pragma unroll
    for (int q = 0; q < NQ; q++) apply_ry(7 - q, qin[q]);
#pragma unroll
    for (int l = 0; l < LL; l++) {
#pragma unroll
        for (int q = 0; q < NQ; q++) {
            apply_ry(7 - q, theta[(l * NQ + q) * 2 + 0]);
            apply_rz(7 - q, theta[(l * NQ + q) * 2 + 1]);
        }
#pragma unroll
        for (int q = 0; q < NQ; q++) {
            int t = (q + 1) & 7;
            apply_cnot(7 - q, 7 - t);
        }
    }

    ushort4 re4, im4, nr4;
    re4.x = f2bf(sr[0]); re4.y = f2bf(sr[1]); re4.z = f2bf(sr[2]); re4.w = f2bf(sr[3]);
    im4.x = f2bf(si[0]); im4.y = f2bf(si[1]); im4.z = f2bf(si[2]); im4.w = f2bf(si[3]);
    nr4.x = f2bf(-sr[0]); nr4.y = f2bf(-sr[1]); nr4.z = f2bf(-sr[2]); nr4.w = f2bf(-sr[3]);
    bf16s* r1 = P1 + (size_t)row * 512;
    bf16s* r2 = P2 + (size_t)row * 512;
    *(ushort4*)(r1 + lane * 4)       = re4;
    *(ushort4*)(r1 + 256 + lane * 4) = im4;
    *(ushort4*)(r2 + lane * 4)       = im4;
    *(ushort4*)(r2 + 256 + lane * 4) = nr4;
}

// ---------------------------------------------------------------------------
// MFMA bf16 GEMM: C[M][N] = A[M][K] @ Bt[N][K]^T (+bias[col]). m97-style.
// 128x128 tile, BK=32, 256 threads = 4 waves, each wave 64x64.
// ---------------------------------------------------------------------------
template<bool OUT_BF16>
__global__ __launch_bounds__(256) void mfma_gemm(
    const bf16s* __restrict__ A, const bf16s* __restrict__ Bt,
    const float* __restrict__ bias, void* __restrict__ Cv,
    int M, int N, int K,
    long long sA, long long sB, long long sC)
{
    __shared__ bf16s As[128 * 32];
    __shared__ bf16s Bs[128 * 32];

    const int tid  = threadIdx.x;
    const int wave = tid >> 6, lane = tid & 63;
    const int quad = lane >> 4, lr = lane & 15;
    const int wm = (wave >> 1) * 64, wn = (wave & 1) * 64;
    const int m0 = blockIdx.x * 128, n0 = blockIdx.y * 128;

    A  += (size_t)blockIdx.z * sA;
    Bt += (size_t)blockIdx.z * sB;

    f32x4 acc[4][4];
#pragma unroll
    for (int i = 0; i < 4; i++)
#pragma unroll
        for (int j = 0; j < 4; j++) acc[i][j] = (f32x4){0.f, 0.f, 0.f, 0.f};

    for (int kt = 0; kt < K; kt += 32) {
#pragma unroll
        for (int j = 0; j < 2; j++) {
            int ch = j * 256 + tid;
            int row = ch >> 2, kc = (ch & 3) * 8;
            __builtin_amdgcn_global_load_lds(
                (AS1 const void*)(A + (size_t)(m0 + row) * K + kt + kc),
                (AS3 void*)(As + (size_t)(j * 256 + wave * 64) * 8), 16, 0, 0);
            __builtin_amdgcn_global_load_lds(
                (AS1 const void*)(Bt + (size_t)(n0 + row) * K + kt + kc),
                (AS3 void*)(Bs + (size_t)(j * 256 + wave * 64) * 8), 16, 0, 0);
        }
        __syncthreads();

        bf16x8 af[4], bfr[4];
#pragma unroll
        for (int i = 0; i < 4; i++)
            af[i] = *(const bf16x8*)(As + (wm + i * 16 + lr) * 32 + quad * 8);
#pragma unroll
        for (int j = 0; j < 4; j++)
            bfr[j] = *(const bf16x8*)(Bs + (wn + j * 16 + lr) * 32 + quad * 8);
#pragma unroll
        for (int i = 0; i < 4; i++)
#pragma unroll
            for (int j = 0; j < 4; j++)
                acc[i][j] = __builtin_amdgcn_mfma_f32_16x16x32_bf16(
                    af[i], bfr[j], acc[i][j], 0, 0, 0);
        __syncthreads();
    }

    float* Cf = (float*)Cv + (size_t)blockIdx.z * sC;
    bf16s* Cb = (bf16s*)Cv + (size_t)blockIdx.z * sC;
#pragma unroll
    for (int i = 0; i < 4; i++) {
        int row0 = m0 + wm + i * 16 + quad * 4;
#pragma unroll
        for (int j = 0; j < 4; j++) {
            int col = n0 + wn + j * 16 + lr;
            float bb = bias ? bias[col] : 0.f;
#pragma unroll
            for (int r = 0; r < 4; r++) {
                float v = acc[i][j][r] + bb;
                if (OUT_BF16) Cb[(size_t)(row0 + r) * N + col] = f2bf(v);
                else          Cf[(size_t)(row0 + r) * N + col] = v;
            }
        }
    }
}

// ---------------------------------------------------------------------------
// attn: MFMA Gram + fused softmax.
// Block = (64 s-rows, batch). 4 waves; wave w: rows s0+w*16..+15, all 128 cols.
// G_re = P1.P1t ; |G_im| = |P1.P2t|. K = |G|^2*isq + cos. Softmax in-wave
// (row lives in one 16-lane quad group). Writes attn fp32 + attn_bf bf16.
// ---------------------------------------------------------------------------
__global__ __launch_bounds__(256) void attn_kernel(
    const bf16s* __restrict__ P1, const bf16s* __restrict__ P2,
    const float* __restrict__ phi,
    float* __restrict__ attn, bf16s* __restrict__ attn_bf)
{
    __shared__ bf16s As [64 * 32];
    __shared__ bf16s Bs1[128 * 32];
    __shared__ bf16s Bs2[128 * 32];

    const int tid  = threadIdx.x;
    const int wave = tid >> 6, lane = tid & 63;
    const int quad = lane >> 4, lr = lane & 15;
    const int b = blockIdx.y;
    const int s0 = blockIdx.x * 64;
    const bf16s* p1b = P1 + (size_t)b * 128 * 512;
    const bf16s* p2b = P2 + (size_t)b * 128 * 512;

    f32x4 accre[8], accim[8];
#pragma unroll
    for (int j = 0; j < 8; j++) {
        accre[j] = (f32x4){0.f, 0.f, 0.f, 0.f};
        accim[j] = (f32x4){0.f, 0.f, 0.f, 0.f};
    }

    for (int kt = 0; kt < 512; kt += 32) {
        {
            int row = tid >> 2, kc = (tid & 3) * 8;
            __builtin_amdgcn_global_load_lds(
                (AS1 const void*)(p1b + (size_t)(s0 + row) * 512 + kt + kc),
                (AS3 void*)(As + (size_t)(wave * 64) * 8), 16, 0, 0);
        }
#pragma unroll
        for (int j = 0; j < 2; j++) {
            int ch = j * 256 + tid;
            int row = ch >> 2, kc = (ch & 3) * 8;
            __builtin_amdgcn_global_load_lds(
                (AS1 const void*)(p1b + (size_t)row * 512 + kt + kc),
                (AS3 void*)(Bs1 + (size_t)(j * 256 + wave * 64) * 8), 16, 0, 0);
            __builtin_amdgcn_global_load_lds(
                (AS1 const void*)(p2b + (size_t)row * 512 + kt + kc),
                (AS3 void*)(Bs2 + (size_t)(j * 256 + wave * 64) * 8), 16, 0, 0);
        }
        __syncthreads();

        bf16x8 afr = *(const bf16x8*)(As + (wave * 16 + lr) * 32 + quad * 8);
#pragma unroll
        for (int j = 0; j < 8; j++) {
            bf16x8 b1 = *(const bf16x8*)(Bs1 + (j * 16 + lr) * 32 + quad * 8);
            accre[j] = __builtin_amdgcn_mfma_f32_16x16x32_bf16(afr, b1, accre[j], 0, 0, 0);
            bf16x8 b2 = *(const bf16x8*)(Bs2 + (j * 16 + lr) * 32 + quad * 8);
            accim[j] = __builtin_amdgcn_mfma_f32_16x16x32_bf16(afr, b2, accim[j], 0, 0, 0);
        }
        __syncthreads();
    }

    const float isq = 0.35355339059327373f;
    float ph_r[4], ph_c[8];
#pragma unroll
    for (int r = 0; r < 4; r++) ph_r[r] = phi[s0 + wave * 16 + quad * 4 + r];
#pragma unroll
    for (int j = 0; j < 8; j++) ph_c[j] = phi[j * 16 + lr];

#pragma unroll
    for (int r = 0; r < 4; r++) {
        float v[8];
        float mx = -1e30f;
#pragma unroll
        for (int j = 0; j < 8; j++) {
            float re = accre[j][r], im = accim[j][r];
            v[j] = (re * re + im * im) * isq + __cosf(ph_c[j] - ph_r[r]);
            mx = fmaxf(mx, v[j]);
        }
#pragma unroll
        for (int off = 1; off <= 8; off <<= 1) mx = fmaxf(mx, __shfl_xor(mx, off, 64));
        float sm = 0.f;
#pragma unroll
        for (int j = 0; j < 8; j++) { v[j] = __expf(v[j] - mx); sm += v[j]; }
#pragma unroll
        for (int off = 1; off <= 8; off <<= 1) sm += __shfl_xor(sm, off, 64);
        float inv = 1.f / sm;
        int srow = b * 128 + s0 + wave * 16 + quad * 4 + r;
#pragma unroll
        for (int j = 0; j < 8; j++) {
            float o = v[j] * inv;
            attn[(size_t)srow * 128 + j * 16 + lr] = o;
            attn_bf[(size_t)srow * 128 + j * 16 + lr] = f2bf(o);
        }
    }
}

// ---------------------------------------------------------------------------
extern "C" void kernel_launch(void* const* d_in, const int* in_sizes, int n_in,
                              void* d_out, int out_size, void* d_ws, size_t ws_size,
                              hipStream_t stream) {
    const float* X     = (const float*)d_in[0];
    const float* Wi    = (const float*)d_in[1];
    const float* bi    = (const float*)d_in[2];
    const float* Wv    = (const float*)d_in[3];
    const float* bv    = (const float*)d_in[4];
    const float* Wo    = (const float*)d_in[5];
    const float* bo    = (const float*)d_in[6];
    const float* theta = (const float*)d_in[7];
    const float* phi   = (const float*)d_in[8];

    float* y    = (float*)d_out;
    float* attn = y + (size_t)MM * EE;

    bf16s* Xb   = (bf16s*)d_ws;                      // 16384*1024
    bf16s* P1   = Xb  + (size_t)MM * EE;             // 16384*512
    bf16s* P2   = P1  + (size_t)MM * 512;            // 16384*512
    bf16s* Vtb  = P2  + (size_t)MM * 512;            // 128 * 1024*128
    bf16s* o2b  = Vtb + (size_t)MM * EE;             // 16384*1024
    bf16s* abf  = o2b + (size_t)MM * EE;             // 128*128*128
    bf16s* Wvt  = abf + (size_t)BB * SS * SS;        // 1024*1024
    bf16s* Wot  = Wvt + (size_t)EE * EE;             // 1024*1024

    // conversions
    convert_kernel<<<(MM * EE / 4 + 255) / 256, 256, 0, stream>>>(X, Xb, MM * EE / 4);
    transpose_conv_kernel<<<dim3(32, 32), 256, 0, stream>>>(Wv, Wvt, EE, EE);
    transpose_conv_kernel<<<dim3(32, 32), 256, 0, stream>>>(Wo, Wot, EE, EE);
    // psi (bf16 split layouts)
    qsim_kernel<<<MM / 4, 256, 0, stream>>>(X, Wi, bi, theta, P1, P2);
    // Vt_b = Wv^T @ X_b^T : A=Wvt[e][k], Bt=Xb_b[t][k], C=Vt_b[e][t]  (no bias)
    mfma_gemm<true><<<dim3(EE / 128, 1, BB), 256, 0, stream>>>(
        Wvt, Xb, nullptr, Vtb, EE, SS, EE,
        0, (long long)SS * EE, (long long)EE * SS);
    // attn (Gram via MFMA + softmax)
    attn_kernel<<<dim3(2, BB), 256, 0, stream>>>(P1, P2, phi, attn, abf);
    // o2_b = attn_b @ V_b + bv : A=abf_b[t][s], Bt=Vt_b[e][s], bias=bv
    mfma_gemm<true><<<dim3(1, EE / 128, BB), 256, 0, stream>>>(
        abf, Vtb, bv, o2b, SS, EE, SS,
        (long long)SS * SS, (long long)EE * SS, (long long)SS * EE);
    // y = o2 @ Wo + bo
    mfma_gemm<false><<<dim3(MM / 128, EE / 128, 1), 256, 0, stream>>>(
        o2b, Wot, bo, y, MM, EE, EE, 0, 0, 0);
}

// Round 4
// 385.817 us; speedup vs baseline: 3.7571x; 1.0174x over previous
//
#include <hip/hip_runtime.h>
#include <hip/hip_bf16.h>

#define BB 128
#define SS 128
#define EE 1024
#define NQ 8
#define DD 256
#define LL 4
#define MM (BB*SS)

typedef unsigned short bf16s;
typedef __attribute__((ext_vector_type(8))) short bf16x8;
typedef __attribute__((ext_vector_type(4))) float f32x4;

#define AS1 __attribute__((address_space(1)))
#define AS3 __attribute__((address_space(3)))

__device__ __forceinline__ unsigned short f2bf(float x) {
    unsigned u = __float_as_uint(x);
    u += 0x7fffu + ((u >> 16) & 1u);
    return (unsigned short)(u >> 16);
}

// ---------------------------------------------------------------------------
// fp32 RxC -> bf16 CxR transpose-convert (weights)
// ---------------------------------------------------------------------------
__global__ __launch_bounds__(256) void transpose_conv_kernel(
    const float* __restrict__ in, bf16s* __restrict__ out, int R, int C)
{
    __shared__ float t[32][33];
    int bx = blockIdx.x * 32, by = blockIdx.y * 32;
    int lx = threadIdx.x & 31, ly = threadIdx.x >> 5;
#pragma unroll
    for (int i = 0; i < 32; i += 8)
        t[ly + i][lx] = in[(size_t)(by + ly + i) * C + bx + lx];
    __syncthreads();
#pragma unroll
    for (int i = 0; i < 32; i += 8)
        out[(size_t)(bx + ly + i) * R + by + lx] = f2bf(t[lx][ly + i]);
}

// ---------------------------------------------------------------------------
// encode: qin = X@Wi+bi; product state v (bf16); Xb = bf16(X) side-product.
// One wave per sample row.
// ---------------------------------------------------------------------------
__global__ __launch_bounds__(256) void encode_kernel(
    const float* __restrict__ X, const float* __restrict__ Wi,
    const float* __restrict__ bi,
    bf16s* __restrict__ Xb, bf16s* __restrict__ v)
{
    const int lane = threadIdx.x & 63;
    const int wid  = threadIdx.x >> 6;
    const int row  = blockIdx.x * 4 + wid;

    const float* xr = X + (size_t)row * EE;
    bf16s* xbr = Xb + (size_t)row * EE;

    float acc[NQ];
#pragma unroll
    for (int j = 0; j < NQ; j++) acc[j] = 0.f;

#pragma unroll
    for (int t = 0; t < 4; t++) {
        float4 x4 = ((const float4*)xr)[t * 64 + lane];
        ushort4 xo;
        xo.x = f2bf(x4.x); xo.y = f2bf(x4.y); xo.z = f2bf(x4.z); xo.w = f2bf(x4.w);
        ((ushort4*)xbr)[t * 64 + lane] = xo;
        int kbase = t * 256 + lane * 4;
        const float xs[4] = {x4.x, x4.y, x4.z, x4.w};
#pragma unroll
        for (int u = 0; u < 4; u++) {
            const float4* w4 = (const float4*)(Wi + (size_t)(kbase + u) * 8);
            float4 wa = w4[0], wb = w4[1];
            float xv = xs[u];
            acc[0] += xv * wa.x; acc[1] += xv * wa.y; acc[2] += xv * wa.z; acc[3] += xv * wa.w;
            acc[4] += xv * wb.x; acc[5] += xv * wb.y; acc[6] += xv * wb.z; acc[7] += xv * wb.w;
        }
    }
    float qin[NQ];
#pragma unroll
    for (int j = 0; j < NQ; j++) {
        float s = acc[j];
#pragma unroll
        for (int off = 32; off >= 1; off >>= 1) s += __shfl_xor(s, off, 64);
        qin[j] = s + bi[j];
    }

    // product state: amp[idx] = prod_b (bit_b(idx) ? sin : cos)(qin[7-b]/2)
    float cs[NQ], sn[NQ];
#pragma unroll
    for (int q = 0; q < NQ; q++) __sincosf(0.5f * qin[q], &sn[q], &cs[q]);

    float common = 1.f;
#pragma unroll
    for (int b = 2; b < 8; b++) {
        int q = 7 - b;
        common *= ((lane >> (b - 2)) & 1) ? sn[q] : cs[q];
    }
    // cc bit0 -> qubit 7, bit1 -> qubit 6
    float a0 = common * cs[6] * cs[7];
    float a1 = common * cs[6] * sn[7];
    float a2 = common * sn[6] * cs[7];
    float a3 = common * sn[6] * sn[7];
    ushort4 vo;
    vo.x = f2bf(a0); vo.y = f2bf(a1); vo.z = f2bf(a2); vo.w = f2bf(a3);
    ((ushort4*)(v + (size_t)row * DD))[lane] = vo;
}

// ---------------------------------------------------------------------------
// ubuild: simulate the theta-circuit on all 256 basis states -> Ubt bf16.
// Ubt[n][j] (n<256: U_re[n][j]; n>=256: U_im[n-256][j]), j = basis column.
// One wave per column; 64 blocks x 4 waves.
// ---------------------------------------------------------------------------
__global__ __launch_bounds__(256) void ubuild_kernel(
    const float* __restrict__ theta, bf16s* __restrict__ Ubt)
{
    const int lane = threadIdx.x & 63;
    const int wid  = threadIdx.x >> 6;
    const int col  = blockIdx.x * 4 + wid;   // 0..255

    float sr[4], si[4];
#pragma unroll
    for (int c = 0; c < 4; c++) { sr[c] = 0.f; si[c] = 0.f; }
    if (lane == (col >> 2)) sr[col & 3] = 1.f;

    auto apply_ry = [&](int b, float th) {
        float s, c;
        __sincosf(0.5f * th, &s, &c);
        if (b >= 2) {
            int lb = b - 2;
            int bit = (lane >> lb) & 1;
            float sgn = bit ? s : -s;
#pragma unroll
            for (int cc = 0; cc < 4; cc++) {
                float pr = __shfl_xor(sr[cc], 1 << lb, 64);
                float pi = __shfl_xor(si[cc], 1 << lb, 64);
                sr[cc] = c * sr[cc] + sgn * pr;
                si[cc] = c * si[cc] + sgn * pi;
            }
        } else {
            int m = 1 << b;
            float tr[4], ti[4];
#pragma unroll
            for (int cc = 0; cc < 4; cc++) { tr[cc] = sr[cc]; ti[cc] = si[cc]; }
#pragma unroll
            for (int cc = 0; cc < 4; cc++) {
                int bit = (cc >> b) & 1;
                float sgn = bit ? s : -s;
                sr[cc] = c * tr[cc] + sgn * tr[cc ^ m];
                si[cc] = c * ti[cc] + sgn * ti[cc ^ m];
            }
        }
    };
    auto apply_rz = [&](int b, float th) {
        float sz, cr;
        __sincosf(0.5f * th, &sz, &cr);
#pragma unroll
        for (int cc = 0; cc < 4; cc++) {
            int bit = (b >= 2) ? ((lane >> (b - 2)) & 1) : ((cc >> b) & 1);
            float ci = bit ? sz : -sz;
            float r = sr[cc], i = si[cc];
            sr[cc] = r * cr - i * ci;
            si[cc] = r * ci + i * cr;
        }
    };
    auto apply_cnot = [&](int bc, int bt) {
        float pr[4], pi[4];
        if (bt >= 2) {
            int m = 1 << (bt - 2);
#pragma unroll
            for (int cc = 0; cc < 4; cc++) {
                pr[cc] = __shfl_xor(sr[cc], m, 64);
                pi[cc] = __shfl_xor(si[cc], m, 64);
            }
        } else {
            int m = 1 << bt;
#pragma unroll
            for (int cc = 0; cc < 4; cc++) {
                pr[cc] = sr[cc ^ m];
                pi[cc] = si[cc ^ m];
            }
        }
#pragma unroll
        for (int cc = 0; cc < 4; cc++) {
            int ctrl = (bc >= 2) ? ((lane >> (bc - 2)) & 1) : ((cc >> bc) & 1);
            sr[cc] = ctrl ? pr[cc] : sr[cc];
            si[cc] = ctrl ? pi[cc] : si[cc];
        }
    };

#pragma unroll
    for (int l = 0; l < LL; l++) {
#pragma unroll
        for (int q = 0; q < NQ; q++) {
            apply_ry(7 - q, theta[(l * NQ + q) * 2 + 0]);
            apply_rz(7 - q, theta[(l * NQ + q) * 2 + 1]);
        }
#pragma unroll
        for (int q = 0; q < NQ; q++) {
            int t = (q + 1) & 7;
            apply_cnot(7 - q, 7 - t);
        }
    }

#pragma unroll
    for (int cc = 0; cc < 4; cc++) {
        int i = lane * 4 + cc;
        Ubt[(size_t)i * DD + col]         = f2bf(sr[cc]);
        Ubt[(size_t)(i + DD) * DD + col]  = f2bf(si[cc]);
    }
}

// ---------------------------------------------------------------------------
// psi_gemm: C[s][n] = v[s][:] . Ubt[n][:]  (M=16384, N=512, K=256)
// Epilogue writes P1[s][n] = C, and P2: n<256 -> P2[s][n+256] = -C,
// n>=256 -> P2[s][n-256] = C.
// ---------------------------------------------------------------------------
__global__ __launch_bounds__(256) void psi_gemm_kernel(
    const bf16s* __restrict__ A, const bf16s* __restrict__ Bt,
    bf16s* __restrict__ P1, bf16s* __restrict__ P2)
{
    __shared__ bf16s As[128 * 32];
    __shared__ bf16s Bs[128 * 32];

    const int tid  = threadIdx.x;
    const int wave = tid >> 6, lane = tid & 63;
    const int quad = lane >> 4, lr = lane & 15;
    const int wm = (wave >> 1) * 64, wn = (wave & 1) * 64;
    const int m0 = blockIdx.x * 128, n0 = blockIdx.y * 128;
    const int K = DD, N = 2 * DD;

    f32x4 acc[4][4];
#pragma unroll
    for (int i = 0; i < 4; i++)
#pragma unroll
        for (int j = 0; j < 4; j++) acc[i][j] = (f32x4){0.f, 0.f, 0.f, 0.f};

    for (int kt = 0; kt < K; kt += 32) {
#pragma unroll
        for (int j = 0; j < 2; j++) {
            int ch = j * 256 + tid;
            int row = ch >> 2, kc = (ch & 3) * 8;
            __builtin_amdgcn_global_load_lds(
                (AS1 const void*)(A + (size_t)(m0 + row) * K + kt + kc),
                (AS3 void*)(As + (size_t)(j * 256 + wave * 64) * 8), 16, 0, 0);
            __builtin_amdgcn_global_load_lds(
                (AS1 const void*)(Bt + (size_t)(n0 + row) * K + kt + kc),
                (AS3 void*)(Bs + (size_t)(j * 256 + wave * 64) * 8), 16, 0, 0);
        }
        __syncthreads();

        bf16x8 af[4], bfr[4];
#pragma unroll
        for (int i = 0; i < 4; i++)
            af[i] = *(const bf16x8*)(As + (wm + i * 16 + lr) * 32 + quad * 8);
#pragma unroll
        for (int j = 0; j < 4; j++)
            bfr[j] = *(const bf16x8*)(Bs + (wn + j * 16 + lr) * 32 + quad * 8);
#pragma unroll
        for (int i = 0; i < 4; i++)
#pragma unroll
            for (int j = 0; j < 4; j++)
                acc[i][j] = __builtin_amdgcn_mfma_f32_16x16x32_bf16(
                    af[i], bfr[j], acc[i][j], 0, 0, 0);
        __syncthreads();
    }

#pragma unroll
    for (int i = 0; i < 4; i++) {
        int row0 = m0 + wm + i * 16 + quad * 4;
#pragma unroll
        for (int j = 0; j < 4; j++) {
            int col = n0 + wn + j * 16 + lr;
            int c2  = (col < DD) ? (col + DD) : (col - DD);
            float sgn = (col < DD) ? -1.f : 1.f;
#pragma unroll
            for (int r = 0; r < 4; r++) {
                float val = acc[i][j][r];
                P1[(size_t)(row0 + r) * N + col] = f2bf(val);
                P2[(size_t)(row0 + r) * N + c2] = f2bf(sgn * val);
            }
        }
    }
}

// ---------------------------------------------------------------------------
// MFMA bf16 GEMM: C[M][N] = A[M][K] @ Bt[N][K]^T (+bias[col]). m97-style.
// ---------------------------------------------------------------------------
template<bool OUT_BF16>
__global__ __launch_bounds__(256) void mfma_gemm(
    const bf16s* __restrict__ A, const bf16s* __restrict__ Bt,
    const float* __restrict__ bias, void* __restrict__ Cv,
    int M, int N, int K,
    long long sA, long long sB, long long sC)
{
    __shared__ bf16s As[128 * 32];
    __shared__ bf16s Bs[128 * 32];

    const int tid  = threadIdx.x;
    const int wave = tid >> 6, lane = tid & 63;
    const int quad = lane >> 4, lr = lane & 15;
    const int wm = (wave >> 1) * 64, wn = (wave & 1) * 64;
    const int m0 = blockIdx.x * 128, n0 = blockIdx.y * 128;

    A  += (size_t)blockIdx.z * sA;
    Bt += (size_t)blockIdx.z * sB;

    f32x4 acc[4][4];
#pragma unroll
    for (int i = 0; i < 4; i++)
#pragma unroll
        for (int j = 0; j < 4; j++) acc[i][j] = (f32x4){0.f, 0.f, 0.f, 0.f};

    for (int kt = 0; kt < K; kt += 32) {
#pragma unroll
        for (int j = 0; j < 2; j++) {
            int ch = j * 256 + tid;
            int row = ch >> 2, kc = (ch & 3) * 8;
            __builtin_amdgcn_global_load_lds(
                (AS1 const void*)(A + (size_t)(m0 + row) * K + kt + kc),
                (AS3 void*)(As + (size_t)(j * 256 + wave * 64) * 8), 16, 0, 0);
            __builtin_amdgcn_global_load_lds(
                (AS1 const void*)(Bt + (size_t)(n0 + row) * K + kt + kc),
                (AS3 void*)(Bs + (size_t)(j * 256 + wave * 64) * 8), 16, 0, 0);
        }
        __syncthreads();

        bf16x8 af[4], bfr[4];
#pragma unroll
        for (int i = 0; i < 4; i++)
            af[i] = *(const bf16x8*)(As + (wm + i * 16 + lr) * 32 + quad * 8);
#pragma unroll
        for (int j = 0; j < 4; j++)
            bfr[j] = *(const bf16x8*)(Bs + (wn + j * 16 + lr) * 32 + quad * 8);
#pragma unroll
        for (int i = 0; i < 4; i++)
#pragma unroll
            for (int j = 0; j < 4; j++)
                acc[i][j] = __builtin_amdgcn_mfma_f32_16x16x32_bf16(
                    af[i], bfr[j], acc[i][j], 0, 0, 0);
        __syncthreads();
    }

    float* Cf = (float*)Cv + (size_t)blockIdx.z * sC;
    bf16s* Cb = (bf16s*)Cv + (size_t)blockIdx.z * sC;
#pragma unroll
    for (int i = 0; i < 4; i++) {
        int row0 = m0 + wm + i * 16 + quad * 4;
#pragma unroll
        for (int j = 0; j < 4; j++) {
            int col = n0 + wn + j * 16 + lr;
            float bb = bias ? bias[col] : 0.f;
#pragma unroll
            for (int r = 0; r < 4; r++) {
                float v = acc[i][j][r] + bb;
                if (OUT_BF16) Cb[(size_t)(row0 + r) * N + col] = f2bf(v);
                else          Cf[(size_t)(row0 + r) * N + col] = v;
            }
        }
    }
}

// ---------------------------------------------------------------------------
// attn: MFMA Gram + fused softmax. (unchanged from R3)
// ---------------------------------------------------------------------------
__global__ __launch_bounds__(256) void attn_kernel(
    const bf16s* __restrict__ P1, const bf16s* __restrict__ P2,
    const float* __restrict__ phi,
    float* __restrict__ attn, bf16s* __restrict__ attn_bf)
{
    __shared__ bf16s As [64 * 32];
    __shared__ bf16s Bs1[128 * 32];
    __shared__ bf16s Bs2[128 * 32];

    const int tid  = threadIdx.x;
    const int wave = tid >> 6, lane = tid & 63;
    const int quad = lane >> 4, lr = lane & 15;
    const int b = blockIdx.y;
    const int s0 = blockIdx.x * 64;
    const bf16s* p1b = P1 + (size_t)b * 128 * 512;
    const bf16s* p2b = P2 + (size_t)b * 128 * 512;

    f32x4 accre[8], accim[8];
#pragma unroll
    for (int j = 0; j < 8; j++) {
        accre[j] = (f32x4){0.f, 0.f, 0.f, 0.f};
        accim[j] = (f32x4){0.f, 0.f, 0.f, 0.f};
    }

    for (int kt = 0; kt < 512; kt += 32) {
        {
            int row = tid >> 2, kc = (tid & 3) * 8;
            __builtin_amdgcn_global_load_lds(
                (AS1 const void*)(p1b + (size_t)(s0 + row) * 512 + kt + kc),
                (AS3 void*)(As + (size_t)(wave * 64) * 8), 16, 0, 0);
        }
#pragma unroll
        for (int j = 0; j < 2; j++) {
            int ch = j * 256 + tid;
            int row = ch >> 2, kc = (ch & 3) * 8;
            __builtin_amdgcn_global_load_lds(
                (AS1 const void*)(p1b + (size_t)row * 512 + kt + kc),
                (AS3 void*)(Bs1 + (size_t)(j * 256 + wave * 64) * 8), 16, 0, 0);
            __builtin_amdgcn_global_load_lds(
                (AS1 const void*)(p2b + (size_t)row * 512 + kt + kc),
                (AS3 void*)(Bs2 + (size_t)(j * 256 + wave * 64) * 8), 16, 0, 0);
        }
        __syncthreads();

        bf16x8 afr = *(const bf16x8*)(As + (wave * 16 + lr) * 32 + quad * 8);
#pragma unroll
        for (int j = 0; j < 8; j++) {
            bf16x8 b1 = *(const bf16x8*)(Bs1 + (j * 16 + lr) * 32 + quad * 8);
            accre[j] = __builtin_amdgcn_mfma_f32_16x16x32_bf16(afr, b1, accre[j], 0, 0, 0);
            bf16x8 b2 = *(const bf16x8*)(Bs2 + (j * 16 + lr) * 32 + quad * 8);
            accim[j] = __builtin_amdgcn_mfma_f32_16x16x32_bf16(afr, b2, accim[j], 0, 0, 0);
        }
        __syncthreads();
    }

    const float isq = 0.35355339059327373f;
    float ph_r[4], ph_c[8];
#pragma unroll
    for (int r = 0; r < 4; r++) ph_r[r] = phi[s0 + wave * 16 + quad * 4 + r];
#pragma unroll
    for (int j = 0; j < 8; j++) ph_c[j] = phi[j * 16 + lr];

#pragma unroll
    for (int r = 0; r < 4; r++) {
        float v[8];
        float mx = -1e30f;
#pragma unroll
        for (int j = 0; j < 8; j++) {
            float re = accre[j][r], im = accim[j][r];
            v[j] = (re * re + im * im) * isq + __cosf(ph_c[j] - ph_r[r]);
            mx = fmaxf(mx, v[j]);
        }
#pragma unroll
        for (int off = 1; off <= 8; off <<= 1) mx = fmaxf(mx, __shfl_xor(mx, off, 64));
        float sm = 0.f;
#pragma unroll
        for (int j = 0; j < 8; j++) { v[j] = __expf(v[j] - mx); sm += v[j]; }
#pragma unroll
        for (int off = 1; off <= 8; off <<= 1) sm += __shfl_xor(sm, off, 64);
        float inv = 1.f / sm;
        int srow = b * 128 + s0 + wave * 16 + quad * 4 + r;
#pragma unroll
        for (int j = 0; j < 8; j++) {
            float o = v[j] * inv;
            attn[(size_t)srow * 128 + j * 16 + lr] = o;
            attn_bf[(size_t)srow * 128 + j * 16 + lr] = f2bf(o);
        }
    }
}

// ---------------------------------------------------------------------------
extern "C" void kernel_launch(void* const* d_in, const int* in_sizes, int n_in,
                              void* d_out, int out_size, void* d_ws, size_t ws_size,
                              hipStream_t stream) {
    const float* X     = (const float*)d_in[0];
    const float* Wi    = (const float*)d_in[1];
    const float* bi    = (const float*)d_in[2];
    const float* Wv    = (const float*)d_in[3];
    const float* bv    = (const float*)d_in[4];
    const float* Wo    = (const float*)d_in[5];
    const float* bo    = (const float*)d_in[6];
    const float* theta = (const float*)d_in[7];
    const float* phi   = (const float*)d_in[8];

    float* y    = (float*)d_out;
    float* attn = y + (size_t)MM * EE;

    // workspace layout (same footprint as R3: 136 MB)
    bf16s* Xb   = (bf16s*)d_ws;                      // 16384*1024
    bf16s* P1   = Xb  + (size_t)MM * EE;             // 16384*512
    bf16s* P2   = P1  + (size_t)MM * 512;            // 16384*512
    bf16s* Vtb  = P2  + (size_t)MM * 512;            // 128 * 1024*128
    bf16s* o2b  = Vtb + (size_t)MM * EE;             // 16384*1024
    bf16s* abf  = o2b + (size_t)MM * EE;             // 128*128*128
    bf16s* Wvt  = abf + (size_t)BB * SS * SS;        // 1024*1024
    bf16s* Wot  = Wvt + (size_t)EE * EE;             // 1024*1024
    // v and Ubt overlap o2b (o2b is only written AFTER v/Ubt are dead)
    bf16s* v    = o2b;                               // 16384*256
    bf16s* Ubt  = o2b + (size_t)MM * DD;             // 512*256

    // encode: qin -> product state v (bf16) + Xb side-product
    encode_kernel<<<MM / 4, 256, 0, stream>>>(X, Wi, bi, Xb, v);
    // build circuit unitary (theta only)
    ubuild_kernel<<<64, 256, 0, stream>>>(theta, Ubt);
    // weight transposes
    transpose_conv_kernel<<<dim3(32, 32), 256, 0, stream>>>(Wv, Wvt, EE, EE);
    transpose_conv_kernel<<<dim3(32, 32), 256, 0, stream>>>(Wo, Wot, EE, EE);
    // psi = v @ Ubt^T -> P1, P2
    psi_gemm_kernel<<<dim3(MM / 128, 4), 256, 0, stream>>>(v, Ubt, P1, P2);
    // Vt_b = Wv^T @ X_b^T
    mfma_gemm<true><<<dim3(EE / 128, 1, BB), 256, 0, stream>>>(
        Wvt, Xb, nullptr, Vtb, EE, SS, EE,
        0, (long long)SS * EE, (long long)EE * SS);
    // attn (Gram via MFMA + softmax)
    attn_kernel<<<dim3(2, BB), 256, 0, stream>>>(P1, P2, phi, attn, abf);
    // o2_b = attn_b @ V_b + bv
    mfma_gemm<true><<<dim3(1, EE / 128, BB), 256, 0, stream>>>(
        abf, Vtb, bv, o2b, SS, EE, SS,
        (long long)SS * SS, (long long)EE * SS, (long long)SS * EE);
    // y = o2 @ Wo + bo
    mfma_gemm<false><<<dim3(MM / 128, EE / 128, 1), 256, 0, stream>>>(
        o2b, Wot, bo, y, MM, EE, EE, 0, 0, 0);
}

// Round 5
// 359.889 us; speedup vs baseline: 4.0277x; 1.0720x over previous
//
#include <hip/hip_runtime.h>
#include <hip/hip_bf16.h>

#define BB 128
#define SS 128
#define EE 1024
#define NQ 8
#define DD 256
#define LL 4
#define MM (BB*SS)

typedef unsigned short bf16s;
typedef __attribute__((ext_vector_type(8))) short bf16x8;
typedef __attribute__((ext_vector_type(4))) float f32x4;

#define AS1 __attribute__((address_space(1)))
#define AS3 __attribute__((address_space(3)))

__device__ __forceinline__ unsigned short f2bf(float x) {
    unsigned u = __float_as_uint(x);
    u += 0x7fffu + ((u >> 16) & 1u);
    return (unsigned short)(u >> 16);
}

// ---------------------------------------------------------------------------
// fp32 RxC -> bf16 CxR transpose-convert (weights)
// ---------------------------------------------------------------------------
__global__ __launch_bounds__(256) void transpose_conv_kernel(
    const float* __restrict__ in, bf16s* __restrict__ out, int R, int C)
{
    __shared__ float t[32][33];
    int bx = blockIdx.x * 32, by = blockIdx.y * 32;
    int lx = threadIdx.x & 31, ly = threadIdx.x >> 5;
#pragma unroll
    for (int i = 0; i < 32; i += 8)
        t[ly + i][lx] = in[(size_t)(by + ly + i) * C + bx + lx];
    __syncthreads();
#pragma unroll
    for (int i = 0; i < 32; i += 8)
        out[(size_t)(bx + ly + i) * R + by + lx] = f2bf(t[lx][ly + i]);
}

// ---------------------------------------------------------------------------
// Wi[1024][8] -> Wit[8][1024] fp32 (tiny; enables coalesced encode loads)
// ---------------------------------------------------------------------------
__global__ __launch_bounds__(256) void wtrans_kernel(
    const float* __restrict__ Wi, float* __restrict__ Wit)
{
    int g = blockIdx.x * 256 + threadIdx.x;   // 0..8191
    int k = g >> 3, j = g & 7;
    Wit[j * 1024 + k] = Wi[g];
}

// ---------------------------------------------------------------------------
// encode: qin = X@Wi+bi; product state v (bf16); Xb = bf16(X) side-product.
// One wave per sample row. All global accesses lane-consecutive (coalesced).
// ---------------------------------------------------------------------------
__global__ __launch_bounds__(256) void encode_kernel(
    const float* __restrict__ X, const float* __restrict__ Wit,
    const float* __restrict__ bi,
    bf16s* __restrict__ Xb, bf16s* __restrict__ v)
{
    const int lane = threadIdx.x & 63;
    const int wid  = threadIdx.x >> 6;
    const int row  = blockIdx.x * 4 + wid;

    const float* xr = X + (size_t)row * EE;
    bf16s* xbr = Xb + (size_t)row * EE;

    float acc[NQ];
#pragma unroll
    for (int j = 0; j < NQ; j++) acc[j] = 0.f;

#pragma unroll
    for (int t = 0; t < 16; t++) {
        int k = t * 64 + lane;
        float x = xr[k];
        xbr[k] = f2bf(x);
#pragma unroll
        for (int j = 0; j < NQ; j++)
            acc[j] += x * Wit[j * 1024 + k];
    }
    float qin[NQ];
#pragma unroll
    for (int j = 0; j < NQ; j++) {
        float s = acc[j];
#pragma unroll
        for (int off = 32; off >= 1; off >>= 1) s += __shfl_xor(s, off, 64);
        qin[j] = s + bi[j];
    }

    // product state: amp[idx] = prod_b (bit_b(idx) ? sin : cos)(qin[7-b]/2)
    float cs[NQ], sn[NQ];
#pragma unroll
    for (int q = 0; q < NQ; q++) __sincosf(0.5f * qin[q], &sn[q], &cs[q]);

    float common = 1.f;
#pragma unroll
    for (int b = 2; b < 8; b++) {
        int q = 7 - b;
        common *= ((lane >> (b - 2)) & 1) ? sn[q] : cs[q];
    }
    // cc bit0 -> qubit 7, bit1 -> qubit 6
    float a0 = common * cs[6] * cs[7];
    float a1 = common * cs[6] * sn[7];
    float a2 = common * sn[6] * cs[7];
    float a3 = common * sn[6] * sn[7];
    ushort4 vo;
    vo.x = f2bf(a0); vo.y = f2bf(a1); vo.z = f2bf(a2); vo.w = f2bf(a3);
    ((ushort4*)(v + (size_t)row * DD))[lane] = vo;
}

// ---------------------------------------------------------------------------
// ubuild: simulate the theta-circuit on all 256 basis states -> Ubt bf16.
// Ubt[n][j] (n<256: U_re[n][j]; n>=256: U_im[n-256][j]), j = basis column.
// ---------------------------------------------------------------------------
__global__ __launch_bounds__(256) void ubuild_kernel(
    const float* __restrict__ theta, bf16s* __restrict__ Ubt)
{
    const int lane = threadIdx.x & 63;
    const int wid  = threadIdx.x >> 6;
    const int col  = blockIdx.x * 4 + wid;   // 0..255

    float sr[4], si[4];
#pragma unroll
    for (int c = 0; c < 4; c++) { sr[c] = 0.f; si[c] = 0.f; }
    if (lane == (col >> 2)) sr[col & 3] = 1.f;

    auto apply_ry = [&](int b, float th) {
        float s, c;
        __sincosf(0.5f * th, &s, &c);
        if (b >= 2) {
            int lb = b - 2;
            int bit = (lane >> lb) & 1;
            float sgn = bit ? s : -s;
#pragma unroll
            for (int cc = 0; cc < 4; cc++) {
                float pr = __shfl_xor(sr[cc], 1 << lb, 64);
                float pi = __shfl_xor(si[cc], 1 << lb, 64);
                sr[cc] = c * sr[cc] + sgn * pr;
                si[cc] = c * si[cc] + sgn * pi;
            }
        } else {
            int m = 1 << b;
            float tr[4], ti[4];
#pragma unroll
            for (int cc = 0; cc < 4; cc++) { tr[cc] = sr[cc]; ti[cc] = si[cc]; }
#pragma unroll
            for (int cc = 0; cc < 4; cc++) {
                int bit = (cc >> b) & 1;
                float sgn = bit ? s : -s;
                sr[cc] = c * tr[cc] + sgn * tr[cc ^ m];
                si[cc] = c * ti[cc] + sgn * ti[cc ^ m];
            }
        }
    };
    auto apply_rz = [&](int b, float th) {
        float sz, cr;
        __sincosf(0.5f * th, &sz, &cr);
#pragma unroll
        for (int cc = 0; cc < 4; cc++) {
            int bit = (b >= 2) ? ((lane >> (b - 2)) & 1) : ((cc >> b) & 1);
            float ci = bit ? sz : -sz;
            float r = sr[cc], i = si[cc];
            sr[cc] = r * cr - i * ci;
            si[cc] = r * ci + i * cr;
        }
    };
    auto apply_cnot = [&](int bc, int bt) {
        float pr[4], pi[4];
        if (bt >= 2) {
            int m = 1 << (bt - 2);
#pragma unroll
            for (int cc = 0; cc < 4; cc++) {
                pr[cc] = __shfl_xor(sr[cc], m, 64);
                pi[cc] = __shfl_xor(si[cc], m, 64);
            }
        } else {
            int m = 1 << bt;
#pragma unroll
            for (int cc = 0; cc < 4; cc++) {
                pr[cc] = sr[cc ^ m];
                pi[cc] = si[cc ^ m];
            }
        }
#pragma unroll
        for (int cc = 0; cc < 4; cc++) {
            int ctrl = (bc >= 2) ? ((lane >> (bc - 2)) & 1) : ((cc >> bc) & 1);
            sr[cc] = ctrl ? pr[cc] : sr[cc];
            si[cc] = ctrl ? pi[cc] : si[cc];
        }
    };

#pragma unroll
    for (int l = 0; l < LL; l++) {
#pragma unroll
        for (int q = 0; q < NQ; q++) {
            apply_ry(7 - q, theta[(l * NQ + q) * 2 + 0]);
            apply_rz(7 - q, theta[(l * NQ + q) * 2 + 1]);
        }
#pragma unroll
        for (int q = 0; q < NQ; q++) {
            int t = (q + 1) & 7;
            apply_cnot(7 - q, 7 - t);
        }
    }

#pragma unroll
    for (int cc = 0; cc < 4; cc++) {
        int i = lane * 4 + cc;
        Ubt[(size_t)i * DD + col]         = f2bf(sr[cc]);
        Ubt[(size_t)(i + DD) * DD + col]  = f2bf(si[cc]);
    }
}

// ---------------------------------------------------------------------------
// psi_gemm: C[s][n] = v[s][:] . Ubt[n][:]  (M=16384, N=512, K=256)
// Epilogue writes P1[s][n] = C, and P2: n<256 -> P2[s][n+256] = -C,
// n>=256 -> P2[s][n-256] = C.
// ---------------------------------------------------------------------------
__global__ __launch_bounds__(256) void psi_gemm_kernel(
    const bf16s* __restrict__ A, const bf16s* __restrict__ Bt,
    bf16s* __restrict__ P1, bf16s* __restrict__ P2)
{
    __shared__ bf16s As[128 * 32];
    __shared__ bf16s Bs[128 * 32];

    const int tid  = threadIdx.x;
    const int wave = tid >> 6, lane = tid & 63;
    const int quad = lane >> 4, lr = lane & 15;
    const int wm = (wave >> 1) * 64, wn = (wave & 1) * 64;
    const int m0 = blockIdx.x * 128, n0 = blockIdx.y * 128;
    const int K = DD, N = 2 * DD;

    f32x4 acc[4][4];
#pragma unroll
    for (int i = 0; i < 4; i++)
#pragma unroll
        for (int j = 0; j < 4; j++) acc[i][j] = (f32x4){0.f, 0.f, 0.f, 0.f};

    for (int kt = 0; kt < K; kt += 32) {
#pragma unroll
        for (int j = 0; j < 2; j++) {
            int ch = j * 256 + tid;
            int row = ch >> 2, kc = (ch & 3) * 8;
            __builtin_amdgcn_global_load_lds(
                (AS1 const void*)(A + (size_t)(m0 + row) * K + kt + kc),
                (AS3 void*)(As + (size_t)(j * 256 + wave * 64) * 8), 16, 0, 0);
            __builtin_amdgcn_global_load_lds(
                (AS1 const void*)(Bt + (size_t)(n0 + row) * K + kt + kc),
                (AS3 void*)(Bs + (size_t)(j * 256 + wave * 64) * 8), 16, 0, 0);
        }
        __syncthreads();

        bf16x8 af[4], bfr[4];
#pragma unroll
        for (int i = 0; i < 4; i++)
            af[i] = *(const bf16x8*)(As + (wm + i * 16 + lr) * 32 + quad * 8);
#pragma unroll
        for (int j = 0; j < 4; j++)
            bfr[j] = *(const bf16x8*)(Bs + (wn + j * 16 + lr) * 32 + quad * 8);
#pragma unroll
        for (int i = 0; i < 4; i++)
#pragma unroll
            for (int j = 0; j < 4; j++)
                acc[i][j] = __builtin_amdgcn_mfma_f32_16x16x32_bf16(
                    af[i], bfr[j], acc[i][j], 0, 0, 0);
        __syncthreads();
    }

#pragma unroll
    for (int i = 0; i < 4; i++) {
        int row0 = m0 + wm + i * 16 + quad * 4;
#pragma unroll
        for (int j = 0; j < 4; j++) {
            int col = n0 + wn + j * 16 + lr;
            int c2  = (col < DD) ? (col + DD) : (col - DD);
            float sgn = (col < DD) ? -1.f : 1.f;
#pragma unroll
            for (int r = 0; r < 4; r++) {
                float val = acc[i][j][r];
                P1[(size_t)(row0 + r) * N + col] = f2bf(val);
                P2[(size_t)(row0 + r) * N + c2] = f2bf(sgn * val);
            }
        }
    }
}

// ---------------------------------------------------------------------------
// MFMA bf16 GEMM: C[M][N] = A[M][K] @ Bt[N][K]^T (+bias[col]). m97-style.
// ---------------------------------------------------------------------------
template<bool OUT_BF16>
__global__ __launch_bounds__(256) void mfma_gemm(
    const bf16s* __restrict__ A, const bf16s* __restrict__ Bt,
    const float* __restrict__ bias, void* __restrict__ Cv,
    int M, int N, int K,
    long long sA, long long sB, long long sC)
{
    __shared__ bf16s As[128 * 32];
    __shared__ bf16s Bs[128 * 32];

    const int tid  = threadIdx.x;
    const int wave = tid >> 6, lane = tid & 63;
    const int quad = lane >> 4, lr = lane & 15;
    const int wm = (wave >> 1) * 64, wn = (wave & 1) * 64;
    const int m0 = blockIdx.x * 128, n0 = blockIdx.y * 128;

    A  += (size_t)blockIdx.z * sA;
    Bt += (size_t)blockIdx.z * sB;

    f32x4 acc[4][4];
#pragma unroll
    for (int i = 0; i < 4; i++)
#pragma unroll
        for (int j = 0; j < 4; j++) acc[i][j] = (f32x4){0.f, 0.f, 0.f, 0.f};

    for (int kt = 0; kt < K; kt += 32) {
#pragma unroll
        for (int j = 0; j < 2; j++) {
            int ch = j * 256 + tid;
            int row = ch >> 2, kc = (ch & 3) * 8;
            __builtin_amdgcn_global_load_lds(
                (AS1 const void*)(A + (size_t)(m0 + row) * K + kt + kc),
                (AS3 void*)(As + (size_t)(j * 256 + wave * 64) * 8), 16, 0, 0);
            __builtin_amdgcn_global_load_lds(
                (AS1 const void*)(Bt + (size_t)(n0 + row) * K + kt + kc),
                (AS3 void*)(Bs + (size_t)(j * 256 + wave * 64) * 8), 16, 0, 0);
        }
        __syncthreads();

        bf16x8 af[4], bfr[4];
#pragma unroll
        for (int i = 0; i < 4; i++)
            af[i] = *(const bf16x8*)(As + (wm + i * 16 + lr) * 32 + quad * 8);
#pragma unroll
        for (int j = 0; j < 4; j++)
            bfr[j] = *(const bf16x8*)(Bs + (wn + j * 16 + lr) * 32 + quad * 8);
#pragma unroll
        for (int i = 0; i < 4; i++)
#pragma unroll
            for (int j = 0; j < 4; j++)
                acc[i][j] = __builtin_amdgcn_mfma_f32_16x16x32_bf16(
                    af[i], bfr[j], acc[i][j], 0, 0, 0);
        __syncthreads();
    }

    float* Cf = (float*)Cv + (size_t)blockIdx.z * sC;
    bf16s* Cb = (bf16s*)Cv + (size_t)blockIdx.z * sC;
#pragma unroll
    for (int i = 0; i < 4; i++) {
        int row0 = m0 + wm + i * 16 + quad * 4;
#pragma unroll
        for (int j = 0; j < 4; j++) {
            int col = n0 + wn + j * 16 + lr;
            float bb = bias ? bias[col] : 0.f;
#pragma unroll
            for (int r = 0; r < 4; r++) {
                float v = acc[i][j][r] + bb;
                if (OUT_BF16) Cb[(size_t)(row0 + r) * N + col] = f2bf(v);
                else          Cf[(size_t)(row0 + r) * N + col] = v;
            }
        }
    }
}

// ---------------------------------------------------------------------------
// attn: MFMA Gram + fused softmax.
// ---------------------------------------------------------------------------
__global__ __launch_bounds__(256) void attn_kernel(
    const bf16s* __restrict__ P1, const bf16s* __restrict__ P2,
    const float* __restrict__ phi,
    float* __restrict__ attn, bf16s* __restrict__ attn_bf)
{
    __shared__ bf16s As [64 * 32];
    __shared__ bf16s Bs1[128 * 32];
    __shared__ bf16s Bs2[128 * 32];

    const int tid  = threadIdx.x;
    const int wave = tid >> 6, lane = tid & 63;
    const int quad = lane >> 4, lr = lane & 15;
    const int b = blockIdx.y;
    const int s0 = blockIdx.x * 64;
    const bf16s* p1b = P1 + (size_t)b * 128 * 512;
    const bf16s* p2b = P2 + (size_t)b * 128 * 512;

    f32x4 accre[8], accim[8];
#pragma unroll
    for (int j = 0; j < 8; j++) {
        accre[j] = (f32x4){0.f, 0.f, 0.f, 0.f};
        accim[j] = (f32x4){0.f, 0.f, 0.f, 0.f};
    }

    for (int kt = 0; kt < 512; kt += 32) {
        {
            int row = tid >> 2, kc = (tid & 3) * 8;
            __builtin_amdgcn_global_load_lds(
                (AS1 const void*)(p1b + (size_t)(s0 + row) * 512 + kt + kc),
                (AS3 void*)(As + (size_t)(wave * 64) * 8), 16, 0, 0);
        }
#pragma unroll
        for (int j = 0; j < 2; j++) {
            int ch = j * 256 + tid;
            int row = ch >> 2, kc = (ch & 3) * 8;
            __builtin_amdgcn_global_load_lds(
                (AS1 const void*)(p1b + (size_t)row * 512 + kt + kc),
                (AS3 void*)(Bs1 + (size_t)(j * 256 + wave * 64) * 8), 16, 0, 0);
            __builtin_amdgcn_global_load_lds(
                (AS1 const void*)(p2b + (size_t)row * 512 + kt + kc),
                (AS3 void*)(Bs2 + (size_t)(j * 256 + wave * 64) * 8), 16, 0, 0);
        }
        __syncthreads();

        bf16x8 afr = *(const bf16x8*)(As + (wave * 16 + lr) * 32 + quad * 8);
#pragma unroll
        for (int j = 0; j < 8; j++) {
            bf16x8 b1 = *(const bf16x8*)(Bs1 + (j * 16 + lr) * 32 + quad * 8);
            accre[j] = __builtin_amdgcn_mfma_f32_16x16x32_bf16(afr, b1, accre[j], 0, 0, 0);
            bf16x8 b2 = *(const bf16x8*)(Bs2 + (j * 16 + lr) * 32 + quad * 8);
            accim[j] = __builtin_amdgcn_mfma_f32_16x16x32_bf16(afr, b2, accim[j], 0, 0, 0);
        }
        __syncthreads();
    }

    const float isq = 0.35355339059327373f;
    float ph_r[4], ph_c[8];
#pragma unroll
    for (int r = 0; r < 4; r++) ph_r[r] = phi[s0 + wave * 16 + quad * 4 + r];
#pragma unroll
    for (int j = 0; j < 8; j++) ph_c[j] = phi[j * 16 + lr];

#pragma unroll
    for (int r = 0; r < 4; r++) {
        float v[8];
        float mx = -1e30f;
#pragma unroll
        for (int j = 0; j < 8; j++) {
            float re = accre[j][r], im = accim[j][r];
            v[j] = (re * re + im * im) * isq + __cosf(ph_c[j] - ph_r[r]);
            mx = fmaxf(mx, v[j]);
        }
#pragma unroll
        for (int off = 1; off <= 8; off <<= 1) mx = fmaxf(mx, __shfl_xor(mx, off, 64));
        float sm = 0.f;
#pragma unroll
        for (int j = 0; j < 8; j++) { v[j] = __expf(v[j] - mx); sm += v[j]; }
#pragma unroll
        for (int off = 1; off <= 8; off <<= 1) sm += __shfl_xor(sm, off, 64);
        float inv = 1.f / sm;
        int srow = b * 128 + s0 + wave * 16 + quad * 4 + r;
#pragma unroll
        for (int j = 0; j < 8; j++) {
            float o = v[j] * inv;
            attn[(size_t)srow * 128 + j * 16 + lr] = o;
            attn_bf[(size_t)srow * 128 + j * 16 + lr] = f2bf(o);
        }
    }
}

// ---------------------------------------------------------------------------
extern "C" void kernel_launch(void* const* d_in, const int* in_sizes, int n_in,
                              void* d_out, int out_size, void* d_ws, size_t ws_size,
                              hipStream_t stream) {
    const float* X     = (const float*)d_in[0];
    const float* Wi    = (const float*)d_in[1];
    const float* bi    = (const float*)d_in[2];
    const float* Wv    = (const float*)d_in[3];
    const float* bv    = (const float*)d_in[4];
    const float* Wo    = (const float*)d_in[5];
    const float* bo    = (const float*)d_in[6];
    const float* theta = (const float*)d_in[7];
    const float* phi   = (const float*)d_in[8];

    float* y    = (float*)d_out;
    float* attn = y + (size_t)MM * EE;

    bf16s* Xb   = (bf16s*)d_ws;                      // 16384*1024
    bf16s* P1   = Xb  + (size_t)MM * EE;             // 16384*512
    bf16s* P2   = P1  + (size_t)MM * 512;            // 16384*512
    bf16s* Vtb  = P2  + (size_t)MM * 512;            // 128 * 1024*128
    bf16s* o2b  = Vtb + (size_t)MM * EE;             // 16384*1024
    bf16s* abf  = o2b + (size_t)MM * EE;             // 128*128*128
    bf16s* Wvt  = abf + (size_t)BB * SS * SS;        // 1024*1024
    bf16s* Wot  = Wvt + (size_t)EE * EE;             // 1024*1024
    float* Wit  = (float*)(Wot + (size_t)EE * EE);   // 8*1024 fp32 (32 KB)
    // v and Ubt overlap o2b (o2b written only after v/Ubt are dead)
    bf16s* v    = o2b;                               // 16384*256
    bf16s* Ubt  = o2b + (size_t)MM * DD;             // 512*256

    // Wi transpose (coalesced encode loads)
    wtrans_kernel<<<32, 256, 0, stream>>>(Wi, Wit);
    // encode: qin -> product state v (bf16) + Xb side-product
    encode_kernel<<<MM / 4, 256, 0, stream>>>(X, Wit, bi, Xb, v);
    // build circuit unitary (theta only)
    ubuild_kernel<<<64, 256, 0, stream>>>(theta, Ubt);
    // weight transposes
    transpose_conv_kernel<<<dim3(32, 32), 256, 0, stream>>>(Wv, Wvt, EE, EE);
    transpose_conv_kernel<<<dim3(32, 32), 256, 0, stream>>>(Wo, Wot, EE, EE);
    // psi = v @ Ubt^T -> P1, P2
    psi_gemm_kernel<<<dim3(MM / 128, 4), 256, 0, stream>>>(v, Ubt, P1, P2);
    // Vt_b = Wv^T @ X_b^T
    mfma_gemm<true><<<dim3(EE / 128, 1, BB), 256, 0, stream>>>(
        Wvt, Xb, nullptr, Vtb, EE, SS, EE,
        0, (long long)SS * EE, (long long)EE * SS);
    // attn (Gram via MFMA + softmax)
    attn_kernel<<<dim3(2, BB), 256, 0, stream>>>(P1, P2, phi, attn, abf);
    // o2_b = attn_b @ V_b + bv
    mfma_gemm<true><<<dim3(1, EE / 128, BB), 256, 0, stream>>>(
        abf, Vtb, bv, o2b, SS, EE, SS,
        (long long)SS * SS, (long long)EE * SS, (long long)SS * EE);
    // y = o2 @ Wo + bo
    mfma_gemm<false><<<dim3(MM / 128, EE / 128, 1), 256, 0, stream>>>(
        o2b, Wot, bo, y, MM, EE, EE, 0, 0, 0);
}